// Round 4
// baseline (571.130 us; speedup 1.0000x reference)
//
#include <hip/hip_runtime.h>
#include <math.h>

// Problem constants
// B=16, DIM=256, HW=64, G=8, DH=64, DPG=32, TP=8, N=1024 patches, NG=8192
//
// Workspace layout:
//   shorts [0, 33554432)      qattB: bf16 q then att (in place), [n][pos][c]
//                             c = g*64+d, row stride 512. 67 MB.
//   floats [16777216, +65536) vn: normalized sample grid, [ng][s][{x,y}]
//   shorts after that         woH/woL: wo split into bf16 hi/lo, [o][c]
// d_out (64 MB) doubles as the LN/patchify buffer xn.

#define WS_VN  16777216
#define WS_WOT 16842752

typedef __attribute__((ext_vector_type(8))) short short8;  // 8 bf16 (4 VGPRs)
typedef __attribute__((ext_vector_type(4))) float f32x4;   // MFMA C/D frag

__device__ __forceinline__ short f2bf(float f) {           // RNE f32->bf16
  unsigned u = __builtin_bit_cast(unsigned, f);
  u += 0x7fff + ((u >> 16) & 1);
  return (short)(u >> 16);
}
__device__ __forceinline__ float bf2f(short h) {
  return __builtin_bit_cast(float, ((unsigned)(unsigned short)h) << 16);
}

// ---------------- K1: LayerNorm over channels + patchify ----------------
__global__ __launch_bounds__(256) void k1_ln(const float* __restrict__ x,
    const float* __restrict__ ln_g, const float* __restrict__ ln_b,
    float* __restrict__ xn) {
  int blk = blockIdx.x;
  int b = blk >> 6, h = blk & 63;
  int t = threadIdx.x;
  int quarter = t >> 6, wcol = t & 63;
  const float* xrow = x + (size_t)b * (256 * 4096) + h * 64 + wcol;
  float s = 0.f, ss = 0.f;
#pragma unroll 8
  for (int i = 0; i < 64; ++i) {
    float v = xrow[(size_t)(quarter * 64 + i) * 4096];
    s += v; ss += v * v;
  }
  __shared__ float sm[4][64], sq[4][64], mu_s[64], rs_s[64];
  sm[quarter][wcol] = s; sq[quarter][wcol] = ss;
  __syncthreads();
  if (t < 64) {
    float S  = sm[0][t] + sm[1][t] + sm[2][t] + sm[3][t];
    float SS = sq[0][t] + sq[1][t] + sq[2][t] + sq[3][t];
    float mu = S * (1.f / 256.f);
    float var = SS * (1.f / 256.f) - mu * mu;
    mu_s[t] = mu;
    rs_s[t] = 1.f / sqrtf(var + 1e-6f);
  }
  __syncthreads();
  float mu = mu_s[wcol], rs = rs_s[wcol];
  int it = h >> 3, p = h & 7, jt = wcol >> 3, qq = wcol & 7;
  int n = (it * 8 + jt) * 16 + b;           // patch id
  float* xo = xn + (size_t)n * 16384 + p * 8 + qq;
#pragma unroll 8
  for (int i = 0; i < 64; ++i) {
    int c = quarter * 64 + i;
    float v = xrow[(size_t)c * 4096];
    xo[c * 64] = (v - mu) * rs * ln_g[c] + ln_b[c];
  }
}

// ---------------- K2: grouped q-projection + offset net ----------------
// one wave per (n,g). Writes q as bf16 [n][pos][g*64+o] via qs transpose.
__global__ __launch_bounds__(64) void k2_qoff(const float* __restrict__ xn,
    const float* __restrict__ wq, const float* __restrict__ w1,
    const float* __restrict__ b1, const float* __restrict__ w2,
    short* __restrict__ qb, float* __restrict__ vn) {
  int ng = blockIdx.x;
  int n = ng >> 3, g = ng & 7;
  int lane = threadIdx.x;
  __shared__ float qs[64][65];
  __shared__ float os[64][4];
  const float* xb = xn + (size_t)n * 16384 + g * 2048;
  float xr[32];
#pragma unroll
  for (int c = 0; c < 32; ++c) xr[c] = xb[c * 64 + lane];
  const float* wqg = wq + g * 2048;
#pragma unroll 4
  for (int o = 0; o < 64; ++o) {
    float acc = 0.f;
#pragma unroll
    for (int c = 0; c < 32; ++c) acc += wqg[o * 32 + c] * xr[c];
    qs[o][lane] = acc;
  }
  __syncthreads();
  const float* w1c = w1 + lane * 36;
#pragma unroll
  for (int oy = 0; oy < 2; ++oy)
#pragma unroll
    for (int ox = 0; ox < 2; ++ox) {
      float a = 0.f;
#pragma unroll
      for (int ky = 0; ky < 6; ++ky) {
        int iy = oy * 4 - 1 + ky;
        if (iy < 0 || iy > 7) continue;
#pragma unroll
        for (int kx = 0; kx < 6; ++kx) {
          int ix = ox * 4 - 1 + kx;
          if (ix < 0 || ix > 7) continue;
          a += w1c[ky * 6 + kx] * qs[lane][iy * 8 + ix];
        }
      }
      a += b1[lane];
      a = 0.5f * a * (1.f + erff(a * 0.70710678118654752f));
      os[lane][oy * 2 + ox] = a;
    }
  __syncthreads();
  // q writeback: lane = pos row, 64 bf16 contiguous (transpose via qs)
  {
    short* qrow = qb + ((size_t)(n * 64 + lane) * 512 + g * 64);
#pragma unroll
    for (int o8 = 0; o8 < 8; ++o8) {
      short8 v8;
#pragma unroll
      for (int j = 0; j < 8; ++j) v8[j] = f2bf(qs[o8 * 8 + j][lane]);
      *(short8*)&qrow[o8 * 8] = v8;
    }
  }
  if (lane < 8) {
    int oc = lane >> 2, s = lane & 3;
    float a = 0.f;
    for (int o = 0; o < 64; ++o) a += w2[oc * 64 + o] * os[o][s];
    float off = tanhf(a) * 4.f;
    float base = (oc == 0) ? (float)(s & 1) : (float)(s >> 1);
    vn[(size_t)ng * 8 + s * 2 + oc] = 2.f * (base + off) - 1.f;
  }
}

// ------------- K3: grid-sample + k/v proj + attention + CPB(MFMA) -------------
// 4 waves per block, one (n,g) per wave. q/att in bf16 [n][pos][c].
__global__ __launch_bounds__(256) void k3_attn(const float* __restrict__ xn,
    const float* __restrict__ wk, const float* __restrict__ wv,
    const float* __restrict__ vn,
    const float* __restrict__ cw1, const float* __restrict__ cb1,
    const float* __restrict__ cw2, const float* __restrict__ cb2,
    const float* __restrict__ cw3, const float* __restrict__ cb3,
    short* __restrict__ qattB) {
  int w = threadIdx.x >> 6;
  int lane = threadIdx.x & 63;
  int ng = blockIdx.x * 4 + w;
  int n = ng >> 3, g = ng & 7;
  __shared__ alignas(16) float kvs[4][32][4];
  __shared__ alignas(16) float ks[4][64][4];
  __shared__ alignas(16) float vs[4][64][4];
  __shared__ alignas(16) short bfragLDS[512 * 8];  // cw2 B-fragments, 8 KB
  __shared__ float biasS[4][4][64];                // CPB bias per (wave,s,pos)

  // --- block-cooperative: cw2 -> bf16 B-fragments in LDS ---
  {
    int t = threadIdx.x;
#pragma unroll
    for (int rep = 0; rep < 2; ++rep) {
      int slot = t + rep * 256;
      int combo = slot >> 6, ln = slot & 63;
      int kstep = combo >> 2, nt = combo & 3;
      int kbase = kstep * 32 + (ln >> 4) * 8;
      int ncol = nt * 16 + (ln & 15);
      short8 v;
#pragma unroll
      for (int jj = 0; jj < 8; ++jj) v[jj] = f2bf(cw2[(kbase + jj) * 64 + ncol]);
      *(short8*)&bfragLDS[slot * 8] = v;
    }
  }

  const float* vp = vn + (size_t)ng * 8;
  float vx0 = vp[0], vy0 = vp[1], vx1 = vp[2], vy1 = vp[3];
  float vx2 = vp[4], vy2 = vp[5], vx3 = vp[6], vy3 = vp[7];
  // --- bilinear grid-sample ---
  {
    int c = lane & 31, s2 = lane >> 5;
    const float* tile = xn + (size_t)n * 16384 + (g * 32 + c) * 64;
#pragma unroll
    for (int rep = 0; rep < 2; ++rep) {
      int s = s2 + 2 * rep;
      float vxs = (rep == 0) ? (s2 ? vx1 : vx0) : (s2 ? vx3 : vx2);
      float vys = (rep == 0) ? (s2 ? vy1 : vy0) : (s2 ? vy3 : vy2);
      float X = 4.f * vxs + 3.5f, Y = 4.f * vys + 3.5f;
      float x0f = floorf(X), y0f = floorf(Y);
      int x0 = (int)x0f, y0 = (int)y0f;
      float wx1 = X - x0f, wy1 = Y - y0f;
      float acc = 0.f;
      for (int dy = 0; dy < 2; ++dy) {
        int iy = y0 + dy;
        if (iy < 0 || iy > 7) continue;
        float wyv = dy ? wy1 : 1.f - wy1;
        for (int dx = 0; dx < 2; ++dx) {
          int ix = x0 + dx;
          if (ix < 0 || ix > 7) continue;
          float wxv = dx ? wx1 : 1.f - wx1;
          acc += tile[iy * 8 + ix] * wxv * wyv;
        }
      }
      kvs[w][c][s] = acc;
    }
  }
  __syncthreads();
  // --- k, v projection: lane = d ---
  {
    int d = lane;
    float ka0 = 0, ka1 = 0, ka2 = 0, ka3 = 0, va0 = 0, va1 = 0, va2 = 0, va3 = 0;
    const float4* wk4 = (const float4*)(wk + g * 2048 + d * 32);
    const float4* wv4 = (const float4*)(wv + g * 2048 + d * 32);
#pragma unroll
    for (int c4 = 0; c4 < 8; ++c4) {
      float4 a4 = wk4[c4], b4 = wv4[c4];
      float aw[4] = {a4.x, a4.y, a4.z, a4.w};
      float bw[4] = {b4.x, b4.y, b4.z, b4.w};
#pragma unroll
      for (int u = 0; u < 4; ++u) {
        float4 kv4 = *(const float4*)kvs[w][c4 * 4 + u];
        ka0 += aw[u] * kv4.x; ka1 += aw[u] * kv4.y;
        ka2 += aw[u] * kv4.z; ka3 += aw[u] * kv4.w;
        va0 += bw[u] * kv4.x; va1 += bw[u] * kv4.y;
        va2 += bw[u] * kv4.z; va3 += bw[u] * kv4.w;
      }
    }
    ks[w][d][0] = ka0; ks[w][d][1] = ka1; ks[w][d][2] = ka2; ks[w][d][3] = ka3;
    vs[w][d][0] = va0; vs[w][d][1] = va1; vs[w][d][2] = va2; vs[w][d][3] = va3;
  }
  __syncthreads();
  // --- sim = scale * q . k  (q bf16, vectorized 16B loads) ---
  float sim0 = 0, sim1 = 0, sim2 = 0, sim3 = 0;
  short* qrow = qattB + ((size_t)(n * 64 + lane) * 512 + g * 64);
#pragma unroll
  for (int d8 = 0; d8 < 8; ++d8) {
    short8 q8 = *(const short8*)&qrow[d8 * 8];
#pragma unroll
    for (int j = 0; j < 8; ++j) {
      float qv = bf2f(q8[j]);
      float4 k4 = *(const float4*)ks[w][d8 * 8 + j];
      sim0 += qv * k4.x; sim1 += qv * k4.y; sim2 += qv * k4.z; sim3 += qv * k4.w;
    }
  }
  float logit0 = sim0 * 0.125f, logit1 = sim1 * 0.125f;
  float logit2 = sim2 * 0.125f, logit3 = sim3 * 0.125f;

  // --- CPB via MFMA ---
  short8 bf[2][4];
#pragma unroll
  for (int kstep = 0; kstep < 2; ++kstep)
#pragma unroll
    for (int nt = 0; nt < 4; ++nt)
      bf[kstep][nt] = *(const short8*)&bfragLDS[((kstep * 4 + nt) * 64 + lane) * 8];
  int kcol = (lane >> 4) * 8;
  float c1x[16], c1y[16], c1b[16];
#pragma unroll
  for (int ks2 = 0; ks2 < 2; ++ks2)
#pragma unroll
    for (int jj = 0; jj < 8; ++jj) {
      int i = ks2 * 32 + kcol + jj;
      c1x[ks2 * 8 + jj] = cw1[i];
      c1y[ks2 * 8 + jj] = cw1[64 + i];
      c1b[ks2 * 8 + jj] = cb1[i];
    }
  int jme = lane & 15;
  float w3v[4], b2v[4];
#pragma unroll
  for (int nt = 0; nt < 4; ++nt) {
    w3v[nt] = cw3[nt * 16 + jme];
    b2v[nt] = cb2[nt * 16 + jme];
  }
  float gqx = (float)(jme & 7) * (2.f / 7.f) - 1.f;   // invariant across mt4
  float yrow = (float)(jme >> 3);
#pragma unroll
  for (int s = 0; s < 4; ++s) {
    float vxs = (s == 0) ? vx0 : (s == 1) ? vx1 : (s == 2) ? vx2 : vx3;
    float vys = (s == 0) ? vy0 : (s == 1) ? vy1 : (s == 2) ? vy2 : vy3;
    float px = gqx - vxs;
    float tx = copysignf(log1pf(fabsf(px)), px);
    float pre[16];
#pragma unroll
    for (int t2 = 0; t2 < 16; ++t2) pre[t2] = fmaf(tx, c1x[t2], c1b[t2]);
#pragma unroll 1
    for (int mt4 = 0; mt4 < 4; ++mt4) {
      float gqy = (float)(mt4 * 2) * (2.f / 7.f) + yrow * (2.f / 7.f) - 1.f;
      float py = gqy - vys;
      float ty = copysignf(log1pf(fabsf(py)), py);
      short8 af[2];
#pragma unroll
      for (int ks2 = 0; ks2 < 2; ++ks2)
#pragma unroll
        for (int jj = 0; jj < 8; ++jj) {
          float h = fmaxf(fmaf(ty, c1y[ks2 * 8 + jj], pre[ks2 * 8 + jj]), 0.f);
          af[ks2][jj] = f2bf(h);
        }
      f32x4 a0 = {0,0,0,0}, a1 = {0,0,0,0}, a2 = {0,0,0,0}, a3 = {0,0,0,0};
      a0 = __builtin_amdgcn_mfma_f32_16x16x32_bf16(af[0], bf[0][0], a0, 0, 0, 0);
      a0 = __builtin_amdgcn_mfma_f32_16x16x32_bf16(af[1], bf[1][0], a0, 0, 0, 0);
      a1 = __builtin_amdgcn_mfma_f32_16x16x32_bf16(af[0], bf[0][1], a1, 0, 0, 0);
      a1 = __builtin_amdgcn_mfma_f32_16x16x32_bf16(af[1], bf[1][1], a1, 0, 0, 0);
      a2 = __builtin_amdgcn_mfma_f32_16x16x32_bf16(af[0], bf[0][2], a2, 0, 0, 0);
      a2 = __builtin_amdgcn_mfma_f32_16x16x32_bf16(af[1], bf[1][2], a2, 0, 0, 0);
      a3 = __builtin_amdgcn_mfma_f32_16x16x32_bf16(af[0], bf[0][3], a3, 0, 0, 0);
      a3 = __builtin_amdgcn_mfma_f32_16x16x32_bf16(af[1], bf[1][3], a3, 0, 0, 0);
      float part[4];
#pragma unroll
      for (int reg = 0; reg < 4; ++reg) {
        part[reg] = w3v[0] * fmaxf(a0[reg] + b2v[0], 0.f)
                  + w3v[1] * fmaxf(a1[reg] + b2v[1], 0.f)
                  + w3v[2] * fmaxf(a2[reg] + b2v[2], 0.f)
                  + w3v[3] * fmaxf(a3[reg] + b2v[3], 0.f);
      }
#pragma unroll
      for (int st = 1; st < 16; st <<= 1)
#pragma unroll
        for (int reg = 0; reg < 4; ++reg)
          part[reg] += __shfl_xor(part[reg], st, 64);
      if (jme == 0) {
        int posO = mt4 * 16 + (lane >> 4) * 4;
#pragma unroll
        for (int reg = 0; reg < 4; ++reg) biasS[w][s][posO + reg] = part[reg];
      }
    }
  }
  __syncthreads();
  float c3 = cb3[0];
  logit0 += biasS[w][0][lane] + c3;
  logit1 += biasS[w][1][lane] + c3;
  logit2 += biasS[w][2][lane] + c3;
  logit3 += biasS[w][3][lane] + c3;
  float m = fmaxf(fmaxf(logit0, logit1), fmaxf(logit2, logit3));
  float e0 = expf(logit0 - m), e1 = expf(logit1 - m);
  float e2 = expf(logit2 - m), e3 = expf(logit3 - m);
  float inv = 1.f / (e0 + e1 + e2 + e3);
  e0 *= inv; e1 *= inv; e2 *= inv; e3 *= inv;
  // --- out = attn @ v, overwrite q row in place as bf16 ---
#pragma unroll
  for (int d8 = 0; d8 < 8; ++d8) {
    short8 o8;
#pragma unroll
    for (int j = 0; j < 8; ++j) {
      float4 v4 = *(const float4*)vs[w][d8 * 8 + j];
      o8[j] = f2bf(e0 * v4.x + e1 * v4.y + e2 * v4.z + e3 * v4.w);
    }
    *(short8*)&qrow[d8 * 8] = o8;
  }
}

// -------- K4c: split wo (256x512 fp32, [o][c]) into bf16 hi/lo --------
__global__ __launch_bounds__(256) void k4_cvt(const float* __restrict__ wo,
    short* __restrict__ woH, short* __restrict__ woL) {
  int idx = blockIdx.x * 256 + threadIdx.x;   // 131072 total
  float v = wo[idx];
  short hi = f2bf(v);
  woH[idx] = hi;
  woL[idx] = f2bf(v - bf2f(hi));
}

// ---------------- K4: output projection via MFMA, no LDS ----------------
// Per block (one patch n): C[64 pos x 256 o] = att[n] (K=512) @ wo^T.
// A = att bf16 [pos][c] (direct fragment loads); B = woH+woL split.
__global__ __launch_bounds__(256) void k4_mfma(const short* __restrict__ attB,
    const short* __restrict__ woH, const short* __restrict__ woL,
    const float* __restrict__ bo, float* __restrict__ y) {
  int n = blockIdx.x;
  int w = threadIdx.x >> 6;
  int lane = threadIdx.x & 63;
  f32x4 acc[4][4];
#pragma unroll
  for (int mt = 0; mt < 4; ++mt)
#pragma unroll
    for (int nt = 0; nt < 4; ++nt) acc[mt][nt] = (f32x4){0.f, 0.f, 0.f, 0.f};
  const short* ab = attB + (size_t)n * 32768;
  int ncol0 = w * 64 + (lane & 15);
  int mr = lane & 15, kq = (lane >> 4) * 8;
#pragma unroll 2
  for (int kst = 0; kst < 16; ++kst) {
    int k0 = kst * 32 + kq;
    short8 a[4];
#pragma unroll
    for (int mt = 0; mt < 4; ++mt)
      a[mt] = *(const short8*)&ab[(mt * 16 + mr) * 512 + k0];
#pragma unroll
    for (int nt = 0; nt < 4; ++nt) {
      size_t off = (size_t)(ncol0 + nt * 16) * 512 + k0;
      short8 bhi = *(const short8*)&woH[off];
      short8 blo = *(const short8*)&woL[off];
#pragma unroll
      for (int mt = 0; mt < 4; ++mt) {
        acc[mt][nt] = __builtin_amdgcn_mfma_f32_16x16x32_bf16(a[mt], bhi, acc[mt][nt], 0, 0, 0);
        acc[mt][nt] = __builtin_amdgcn_mfma_f32_16x16x32_bf16(a[mt], blo, acc[mt][nt], 0, 0, 0);
      }
    }
  }
  int b = n & 15, jt = (n >> 4) & 7, it = n >> 7;
#pragma unroll
  for (int nt = 0; nt < 4; ++nt) {
    int o = w * 64 + nt * 16 + (lane & 15);
    float bov = bo[o];
    size_t ybase = ((size_t)b * 256 + o) * 4096;
#pragma unroll
    for (int mt = 0; mt < 4; ++mt) {
#pragma unroll
      for (int reg = 0; reg < 4; ++reg) {
        int row = mt * 16 + (lane >> 4) * 4 + reg;
        int h = it * 8 + (row >> 3), wc = jt * 8 + (row & 7);
        y[ybase + h * 64 + wc] = acc[mt][nt][reg] + bov;
      }
    }
  }
}

extern "C" void kernel_launch(void* const* d_in, const int* in_sizes, int n_in,
                              void* d_out, int out_size, void* d_ws, size_t ws_size,
                              hipStream_t stream) {
  (void)in_sizes; (void)n_in; (void)out_size; (void)ws_size;
  const float* x    = (const float*)d_in[0];
  const float* ln_g = (const float*)d_in[1];
  const float* ln_b = (const float*)d_in[2];
  const float* wq   = (const float*)d_in[3];
  const float* wk   = (const float*)d_in[4];
  const float* wv   = (const float*)d_in[5];
  const float* ow1  = (const float*)d_in[6];
  const float* ob1  = (const float*)d_in[7];
  const float* ow2  = (const float*)d_in[8];
  const float* cw1  = (const float*)d_in[9];
  const float* cb1  = (const float*)d_in[10];
  const float* cw2  = (const float*)d_in[11];
  const float* cb2  = (const float*)d_in[12];
  const float* cw3  = (const float*)d_in[13];
  const float* cb3  = (const float*)d_in[14];
  const float* wo   = (const float*)d_in[15];
  const float* bo   = (const float*)d_in[16];
  float* y  = (float*)d_out;
  float* ws = (float*)d_ws;
  short* qattB = (short*)ws;               // 33,554,432 bf16 (q then att)
  float* vnb   = ws + WS_VN;               // 65,536 floats
  short* woH   = (short*)(ws + WS_WOT);    // 131072 shorts
  short* woL   = woH + 131072;             // 131072 shorts
  float* xn = y;                           // reuse d_out as LN/patchify scratch

  k4_cvt<<<512, 256, 0, stream>>>(wo, woH, woL);
  k1_ln<<<1024, 256, 0, stream>>>(x, ln_g, ln_b, xn);
  k2_qoff<<<8192, 64, 0, stream>>>(xn, wq, ow1, ob1, ow2, qattB, vnb);
  k3_attn<<<2048, 256, 0, stream>>>(xn, wk, wv, vnb, cw1, cb1, cw2, cb2,
                                    cw3, cb3, qattB);
  k4_mfma<<<1024, 256, 0, stream>>>(qattB, woH, woL, bo, y);
}

// Round 5
// 490.180 us; speedup vs baseline: 1.1651x; 1.1651x over previous
//
#include <hip/hip_runtime.h>
#include <math.h>

// Problem constants
// B=16, DIM=256, HW=64, G=8, DH=64, DPG=32, TP=8, N=1024 patches, NG=8192
//
// Workspace layout:
//   shorts [0, 33554432)      qattB: bf16 q then att (in place), [n][pos][c]
//                             c = g*64+d, row stride 512. 67 MB.
//   floats [16777216, +65536) vn: normalized sample grid, [ng][s][{x,y}]
//   shorts after that         woH/woL: wo split into bf16 hi/lo, [o][c]
// d_out (64 MB) doubles as the LN/patchify buffer xn.

#define WS_VN  16777216
#define WS_WOT 16842752

typedef __attribute__((ext_vector_type(8))) short short8;  // 8 bf16 (4 VGPRs)
typedef __attribute__((ext_vector_type(4))) float f32x4;   // MFMA C/D frag

__device__ __forceinline__ short f2bf(float f) {           // RNE f32->bf16
  unsigned u = __builtin_bit_cast(unsigned, f);
  u += 0x7fff + ((u >> 16) & 1);
  return (short)(u >> 16);
}
__device__ __forceinline__ float bf2f(short h) {
  return __builtin_bit_cast(float, ((unsigned)(unsigned short)h) << 16);
}

// ---------------- K1: LayerNorm over channels + patchify ----------------
__global__ __launch_bounds__(256) void k1_ln(const float* __restrict__ x,
    const float* __restrict__ ln_g, const float* __restrict__ ln_b,
    float* __restrict__ xn) {
  int blk = blockIdx.x;
  int b = blk >> 6, h = blk & 63;
  int t = threadIdx.x;
  int quarter = t >> 6, wcol = t & 63;
  const float* xrow = x + (size_t)b * (256 * 4096) + h * 64 + wcol;
  float s = 0.f, ss = 0.f;
#pragma unroll 8
  for (int i = 0; i < 64; ++i) {
    float v = xrow[(size_t)(quarter * 64 + i) * 4096];
    s += v; ss += v * v;
  }
  __shared__ float sm[4][64], sq[4][64], mu_s[64], rs_s[64];
  sm[quarter][wcol] = s; sq[quarter][wcol] = ss;
  __syncthreads();
  if (t < 64) {
    float S  = sm[0][t] + sm[1][t] + sm[2][t] + sm[3][t];
    float SS = sq[0][t] + sq[1][t] + sq[2][t] + sq[3][t];
    float mu = S * (1.f / 256.f);
    float var = SS * (1.f / 256.f) - mu * mu;
    mu_s[t] = mu;
    rs_s[t] = 1.f / sqrtf(var + 1e-6f);
  }
  __syncthreads();
  float mu = mu_s[wcol], rs = rs_s[wcol];
  int it = h >> 3, p = h & 7, jt = wcol >> 3, qq = wcol & 7;
  int n = (it * 8 + jt) * 16 + b;           // patch id
  float* xo = xn + (size_t)n * 16384 + p * 8 + qq;
#pragma unroll 8
  for (int i = 0; i < 64; ++i) {
    int c = quarter * 64 + i;
    float v = xrow[(size_t)c * 4096];
    xo[c * 64] = (v - mu) * rs * ln_g[c] + ln_b[c];
  }
}

// ---------------- K2: grouped q-projection + offset net ----------------
// one wave per (n,g). Writes q as bf16 [n][pos][g*64+o] via qs transpose.
__global__ __launch_bounds__(64) void k2_qoff(const float* __restrict__ xn,
    const float* __restrict__ wq, const float* __restrict__ w1,
    const float* __restrict__ b1, const float* __restrict__ w2,
    short* __restrict__ qb, float* __restrict__ vn) {
  int ng = blockIdx.x;
  int n = ng >> 3, g = ng & 7;
  int lane = threadIdx.x;
  __shared__ float qs[64][65];
  __shared__ float os[64][4];
  const float* xb = xn + (size_t)n * 16384 + g * 2048;
  float xr[32];
#pragma unroll
  for (int c = 0; c < 32; ++c) xr[c] = xb[c * 64 + lane];
  const float* wqg = wq + g * 2048;
#pragma unroll 4
  for (int o = 0; o < 64; ++o) {
    float acc = 0.f;
#pragma unroll
    for (int c = 0; c < 32; ++c) acc += wqg[o * 32 + c] * xr[c];
    qs[o][lane] = acc;
  }
  __syncthreads();
  const float* w1c = w1 + lane * 36;
#pragma unroll
  for (int oy = 0; oy < 2; ++oy)
#pragma unroll
    for (int ox = 0; ox < 2; ++ox) {
      float a = 0.f;
#pragma unroll
      for (int ky = 0; ky < 6; ++ky) {
        int iy = oy * 4 - 1 + ky;
        if (iy < 0 || iy > 7) continue;
#pragma unroll
        for (int kx = 0; kx < 6; ++kx) {
          int ix = ox * 4 - 1 + kx;
          if (ix < 0 || ix > 7) continue;
          a += w1c[ky * 6 + kx] * qs[lane][iy * 8 + ix];
        }
      }
      a += b1[lane];
      a = 0.5f * a * (1.f + erff(a * 0.70710678118654752f));
      os[lane][oy * 2 + ox] = a;
    }
  __syncthreads();
  // q writeback: lane = pos row, 64 bf16 contiguous (transpose via qs)
  {
    short* qrow = qb + ((size_t)(n * 64 + lane) * 512 + g * 64);
#pragma unroll
    for (int o8 = 0; o8 < 8; ++o8) {
      short8 v8;
#pragma unroll
      for (int j = 0; j < 8; ++j) v8[j] = f2bf(qs[o8 * 8 + j][lane]);
      *(short8*)&qrow[o8 * 8] = v8;
    }
  }
  if (lane < 8) {
    int oc = lane >> 2, s = lane & 3;
    float a = 0.f;
    for (int o = 0; o < 64; ++o) a += w2[oc * 64 + o] * os[o][s];
    float off = tanhf(a) * 4.f;
    float base = (oc == 0) ? (float)(s & 1) : (float)(s >> 1);
    vn[(size_t)ng * 8 + s * 2 + oc] = 2.f * (base + off) - 1.f;
  }
}

// ------------- K3: grid-sample + k/v proj + attention + CPB(MFMA) -------------
// 4 waves per block, one (n,g) per wave. q/att in bf16 [n][pos][c].
// __launch_bounds__(256,3): cap VGPRs (~170) -> 3 waves/EU; R4's 256-VGPR
// allocation (full s-unroll) cratered occupancy to 11%.
__global__ __launch_bounds__(256, 3) void k3_attn(const float* __restrict__ xn,
    const float* __restrict__ wk, const float* __restrict__ wv,
    const float* __restrict__ vn,
    const float* __restrict__ cw1, const float* __restrict__ cb1,
    const float* __restrict__ cw2, const float* __restrict__ cb2,
    const float* __restrict__ cw3, const float* __restrict__ cb3,
    short* __restrict__ qattB) {
  int w = threadIdx.x >> 6;
  int lane = threadIdx.x & 63;
  int ng = blockIdx.x * 4 + w;
  int n = ng >> 3, g = ng & 7;
  __shared__ alignas(16) float kvs[4][32][4];
  __shared__ alignas(16) float ks[4][64][4];
  __shared__ alignas(16) float vs[4][64][4];
  __shared__ alignas(16) short bfragLDS[512 * 8];  // cw2 B-fragments, 8 KB
  __shared__ float biasS[4][4][64];                // CPB bias per (wave,s,pos)

  // --- block-cooperative: cw2 -> bf16 B-fragments in LDS ---
  {
    int t = threadIdx.x;
#pragma unroll
    for (int rep = 0; rep < 2; ++rep) {
      int slot = t + rep * 256;
      int combo = slot >> 6, ln = slot & 63;
      int kstep = combo >> 2, nt = combo & 3;
      int kbase = kstep * 32 + (ln >> 4) * 8;
      int ncol = nt * 16 + (ln & 15);
      short8 v;
#pragma unroll
      for (int jj = 0; jj < 8; ++jj) v[jj] = f2bf(cw2[(kbase + jj) * 64 + ncol]);
      *(short8*)&bfragLDS[slot * 8] = v;
    }
  }

  const float* vp = vn + (size_t)ng * 8;
  float vx0 = vp[0], vy0 = vp[1], vx1 = vp[2], vy1 = vp[3];
  float vx2 = vp[4], vy2 = vp[5], vx3 = vp[6], vy3 = vp[7];
  // --- bilinear grid-sample ---
  {
    int c = lane & 31, s2 = lane >> 5;
    const float* tile = xn + (size_t)n * 16384 + (g * 32 + c) * 64;
#pragma unroll
    for (int rep = 0; rep < 2; ++rep) {
      int s = s2 + 2 * rep;
      float vxs = (rep == 0) ? (s2 ? vx1 : vx0) : (s2 ? vx3 : vx2);
      float vys = (rep == 0) ? (s2 ? vy1 : vy0) : (s2 ? vy3 : vy2);
      float X = 4.f * vxs + 3.5f, Y = 4.f * vys + 3.5f;
      float x0f = floorf(X), y0f = floorf(Y);
      int x0 = (int)x0f, y0 = (int)y0f;
      float wx1 = X - x0f, wy1 = Y - y0f;
      float acc = 0.f;
      for (int dy = 0; dy < 2; ++dy) {
        int iy = y0 + dy;
        if (iy < 0 || iy > 7) continue;
        float wyv = dy ? wy1 : 1.f - wy1;
        for (int dx = 0; dx < 2; ++dx) {
          int ix = x0 + dx;
          if (ix < 0 || ix > 7) continue;
          float wxv = dx ? wx1 : 1.f - wx1;
          acc += tile[iy * 8 + ix] * wxv * wyv;
        }
      }
      kvs[w][c][s] = acc;
    }
  }
  __syncthreads();
  // --- k, v projection: lane = d ---
  {
    int d = lane;
    float ka0 = 0, ka1 = 0, ka2 = 0, ka3 = 0, va0 = 0, va1 = 0, va2 = 0, va3 = 0;
    const float4* wk4 = (const float4*)(wk + g * 2048 + d * 32);
    const float4* wv4 = (const float4*)(wv + g * 2048 + d * 32);
#pragma unroll
    for (int c4 = 0; c4 < 8; ++c4) {
      float4 a4 = wk4[c4], b4 = wv4[c4];
      float aw[4] = {a4.x, a4.y, a4.z, a4.w};
      float bw[4] = {b4.x, b4.y, b4.z, b4.w};
#pragma unroll
      for (int u = 0; u < 4; ++u) {
        float4 kv4 = *(const float4*)kvs[w][c4 * 4 + u];
        ka0 += aw[u] * kv4.x; ka1 += aw[u] * kv4.y;
        ka2 += aw[u] * kv4.z; ka3 += aw[u] * kv4.w;
        va0 += bw[u] * kv4.x; va1 += bw[u] * kv4.y;
        va2 += bw[u] * kv4.z; va3 += bw[u] * kv4.w;
      }
    }
    ks[w][d][0] = ka0; ks[w][d][1] = ka1; ks[w][d][2] = ka2; ks[w][d][3] = ka3;
    vs[w][d][0] = va0; vs[w][d][1] = va1; vs[w][d][2] = va2; vs[w][d][3] = va3;
  }
  __syncthreads();
  // --- sim = scale * q . k  (q bf16, vectorized 16B loads) ---
  float sim0 = 0, sim1 = 0, sim2 = 0, sim3 = 0;
  short* qrow = qattB + ((size_t)(n * 64 + lane) * 512 + g * 64);
#pragma unroll 2
  for (int d8 = 0; d8 < 8; ++d8) {
    short8 q8 = *(const short8*)&qrow[d8 * 8];
#pragma unroll
    for (int j = 0; j < 8; ++j) {
      float qv = bf2f(q8[j]);
      float4 k4 = *(const float4*)ks[w][d8 * 8 + j];
      sim0 += qv * k4.x; sim1 += qv * k4.y; sim2 += qv * k4.z; sim3 += qv * k4.w;
    }
  }
  float logit0 = sim0 * 0.125f, logit1 = sim1 * 0.125f;
  float logit2 = sim2 * 0.125f, logit3 = sim3 * 0.125f;

  // --- CPB via MFMA ---
  short8 bf[2][4];
#pragma unroll
  for (int kstep = 0; kstep < 2; ++kstep)
#pragma unroll
    for (int nt = 0; nt < 4; ++nt)
      bf[kstep][nt] = *(const short8*)&bfragLDS[((kstep * 4 + nt) * 64 + lane) * 8];
  int kcol = (lane >> 4) * 8;
  float c1x[16], c1y[16], c1b[16];
#pragma unroll
  for (int ks2 = 0; ks2 < 2; ++ks2)
#pragma unroll
    for (int jj = 0; jj < 8; ++jj) {
      int i = ks2 * 32 + kcol + jj;
      c1x[ks2 * 8 + jj] = cw1[i];
      c1y[ks2 * 8 + jj] = cw1[64 + i];
      c1b[ks2 * 8 + jj] = cb1[i];
    }
  int jme = lane & 15;
  float w3v[4], b2v[4];
#pragma unroll
  for (int nt = 0; nt < 4; ++nt) {
    w3v[nt] = cw3[nt * 16 + jme];
    b2v[nt] = cb2[nt * 16 + jme];
  }
  float gqx = (float)(jme & 7) * (2.f / 7.f) - 1.f;   // invariant across mt4
  float yrow = (float)(jme >> 3);
#pragma unroll 1
  for (int s = 0; s < 4; ++s) {
    float vxs = (s == 0) ? vx0 : (s == 1) ? vx1 : (s == 2) ? vx2 : vx3;
    float vys = (s == 0) ? vy0 : (s == 1) ? vy1 : (s == 2) ? vy2 : vy3;
    float px = gqx - vxs;
    float tx = copysignf(log1pf(fabsf(px)), px);
    float pre[16];
#pragma unroll
    for (int t2 = 0; t2 < 16; ++t2) pre[t2] = fmaf(tx, c1x[t2], c1b[t2]);
#pragma unroll 1
    for (int mt4 = 0; mt4 < 4; ++mt4) {
      float gqy = (float)(mt4 * 2) * (2.f / 7.f) + yrow * (2.f / 7.f) - 1.f;
      float py = gqy - vys;
      float ty = copysignf(log1pf(fabsf(py)), py);
      short8 af[2];
#pragma unroll
      for (int ks2 = 0; ks2 < 2; ++ks2)
#pragma unroll
        for (int jj = 0; jj < 8; ++jj) {
          float h = fmaxf(fmaf(ty, c1y[ks2 * 8 + jj], pre[ks2 * 8 + jj]), 0.f);
          af[ks2][jj] = f2bf(h);
        }
      f32x4 a0 = {0,0,0,0}, a1 = {0,0,0,0}, a2 = {0,0,0,0}, a3 = {0,0,0,0};
      a0 = __builtin_amdgcn_mfma_f32_16x16x32_bf16(af[0], bf[0][0], a0, 0, 0, 0);
      a0 = __builtin_amdgcn_mfma_f32_16x16x32_bf16(af[1], bf[1][0], a0, 0, 0, 0);
      a1 = __builtin_amdgcn_mfma_f32_16x16x32_bf16(af[0], bf[0][1], a1, 0, 0, 0);
      a1 = __builtin_amdgcn_mfma_f32_16x16x32_bf16(af[1], bf[1][1], a1, 0, 0, 0);
      a2 = __builtin_amdgcn_mfma_f32_16x16x32_bf16(af[0], bf[0][2], a2, 0, 0, 0);
      a2 = __builtin_amdgcn_mfma_f32_16x16x32_bf16(af[1], bf[1][2], a2, 0, 0, 0);
      a3 = __builtin_amdgcn_mfma_f32_16x16x32_bf16(af[0], bf[0][3], a3, 0, 0, 0);
      a3 = __builtin_amdgcn_mfma_f32_16x16x32_bf16(af[1], bf[1][3], a3, 0, 0, 0);
      float part[4];
#pragma unroll
      for (int reg = 0; reg < 4; ++reg) {
        part[reg] = w3v[0] * fmaxf(a0[reg] + b2v[0], 0.f)
                  + w3v[1] * fmaxf(a1[reg] + b2v[1], 0.f)
                  + w3v[2] * fmaxf(a2[reg] + b2v[2], 0.f)
                  + w3v[3] * fmaxf(a3[reg] + b2v[3], 0.f);
      }
#pragma unroll
      for (int st = 1; st < 16; st <<= 1)
#pragma unroll
        for (int reg = 0; reg < 4; ++reg)
          part[reg] += __shfl_xor(part[reg], st, 64);
      if (jme == 0) {
        int posO = mt4 * 16 + (lane >> 4) * 4;
#pragma unroll
        for (int reg = 0; reg < 4; ++reg) biasS[w][s][posO + reg] = part[reg];
      }
    }
  }
  __syncthreads();
  float c3 = cb3[0];
  logit0 += biasS[w][0][lane] + c3;
  logit1 += biasS[w][1][lane] + c3;
  logit2 += biasS[w][2][lane] + c3;
  logit3 += biasS[w][3][lane] + c3;
  float m = fmaxf(fmaxf(logit0, logit1), fmaxf(logit2, logit3));
  float e0 = expf(logit0 - m), e1 = expf(logit1 - m);
  float e2 = expf(logit2 - m), e3 = expf(logit3 - m);
  float inv = 1.f / (e0 + e1 + e2 + e3);
  e0 *= inv; e1 *= inv; e2 *= inv; e3 *= inv;
  // --- out = attn @ v, overwrite q row in place as bf16 ---
#pragma unroll 2
  for (int d8 = 0; d8 < 8; ++d8) {
    short8 o8;
#pragma unroll
    for (int j = 0; j < 8; ++j) {
      float4 v4 = *(const float4*)vs[w][d8 * 8 + j];
      o8[j] = f2bf(e0 * v4.x + e1 * v4.y + e2 * v4.z + e3 * v4.w);
    }
    *(short8*)&qrow[d8 * 8] = o8;
  }
}

// -------- K4c: split wo (256x512 fp32, [o][c]) into bf16 hi/lo --------
__global__ __launch_bounds__(256) void k4_cvt(const float* __restrict__ wo,
    short* __restrict__ woH, short* __restrict__ woL) {
  int idx = blockIdx.x * 256 + threadIdx.x;   // 131072 total
  float v = wo[idx];
  short hi = f2bf(v);
  woH[idx] = hi;
  woL[idx] = f2bf(v - bf2f(hi));
}

// ---------------- K4: output projection via MFMA, no LDS ----------------
__global__ __launch_bounds__(256) void k4_mfma(const short* __restrict__ attB,
    const short* __restrict__ woH, const short* __restrict__ woL,
    const float* __restrict__ bo, float* __restrict__ y) {
  int n = blockIdx.x;
  int w = threadIdx.x >> 6;
  int lane = threadIdx.x & 63;
  f32x4 acc[4][4];
#pragma unroll
  for (int mt = 0; mt < 4; ++mt)
#pragma unroll
    for (int nt = 0; nt < 4; ++nt) acc[mt][nt] = (f32x4){0.f, 0.f, 0.f, 0.f};
  const short* ab = attB + (size_t)n * 32768;
  int ncol0 = w * 64 + (lane & 15);
  int mr = lane & 15, kq = (lane >> 4) * 8;
#pragma unroll 2
  for (int kst = 0; kst < 16; ++kst) {
    int k0 = kst * 32 + kq;
    short8 a[4];
#pragma unroll
    for (int mt = 0; mt < 4; ++mt)
      a[mt] = *(const short8*)&ab[(mt * 16 + mr) * 512 + k0];
#pragma unroll
    for (int nt = 0; nt < 4; ++nt) {
      size_t off = (size_t)(ncol0 + nt * 16) * 512 + k0;
      short8 bhi = *(const short8*)&woH[off];
      short8 blo = *(const short8*)&woL[off];
#pragma unroll
      for (int mt = 0; mt < 4; ++mt) {
        acc[mt][nt] = __builtin_amdgcn_mfma_f32_16x16x32_bf16(a[mt], bhi, acc[mt][nt], 0, 0, 0);
        acc[mt][nt] = __builtin_amdgcn_mfma_f32_16x16x32_bf16(a[mt], blo, acc[mt][nt], 0, 0, 0);
      }
    }
  }
  int b = n & 15, jt = (n >> 4) & 7, it = n >> 7;
#pragma unroll
  for (int nt = 0; nt < 4; ++nt) {
    int o = w * 64 + nt * 16 + (lane & 15);
    float bov = bo[o];
    size_t ybase = ((size_t)b * 256 + o) * 4096;
#pragma unroll
    for (int mt = 0; mt < 4; ++mt) {
#pragma unroll
      for (int reg = 0; reg < 4; ++reg) {
        int row = mt * 16 + (lane >> 4) * 4 + reg;
        int h = it * 8 + (row >> 3), wc = jt * 8 + (row & 7);
        y[ybase + h * 64 + wc] = acc[mt][nt][reg] + bov;
      }
    }
  }
}

extern "C" void kernel_launch(void* const* d_in, const int* in_sizes, int n_in,
                              void* d_out, int out_size, void* d_ws, size_t ws_size,
                              hipStream_t stream) {
  (void)in_sizes; (void)n_in; (void)out_size; (void)ws_size;
  const float* x    = (const float*)d_in[0];
  const float* ln_g = (const float*)d_in[1];
  const float* ln_b = (const float*)d_in[2];
  const float* wq   = (const float*)d_in[3];
  const float* wk   = (const float*)d_in[4];
  const float* wv   = (const float*)d_in[5];
  const float* ow1  = (const float*)d_in[6];
  const float* ob1  = (const float*)d_in[7];
  const float* ow2  = (const float*)d_in[8];
  const float* cw1  = (const float*)d_in[9];
  const float* cb1  = (const float*)d_in[10];
  const float* cw2  = (const float*)d_in[11];
  const float* cb2  = (const float*)d_in[12];
  const float* cw3  = (const float*)d_in[13];
  const float* cb3  = (const float*)d_in[14];
  const float* wo   = (const float*)d_in[15];
  const float* bo   = (const float*)d_in[16];
  float* y  = (float*)d_out;
  float* ws = (float*)d_ws;
  short* qattB = (short*)ws;               // 33,554,432 bf16 (q then att)
  float* vnb   = ws + WS_VN;               // 65,536 floats
  short* woH   = (short*)(ws + WS_WOT);    // 131072 shorts
  short* woL   = woH + 131072;             // 131072 shorts
  float* xn = y;                           // reuse d_out as LN/patchify scratch

  k4_cvt<<<512, 256, 0, stream>>>(wo, woH, woL);
  k1_ln<<<1024, 256, 0, stream>>>(x, ln_g, ln_b, xn);
  k2_qoff<<<8192, 64, 0, stream>>>(xn, wq, ow1, ob1, ow2, qattB, vnb);
  k3_attn<<<2048, 256, 0, stream>>>(xn, wk, wv, vnb, cw1, cb1, cw2, cb2,
                                    cw3, cb3, qattB);
  k4_mfma<<<1024, 256, 0, stream>>>(qattB, woH, woL, bo, y);
}